// Round 3
// baseline (174.838 us; speedup 1.0000x reference)
//
#include <hip/hip_runtime.h>

#define DEVI __device__ __forceinline__

typedef short bf16x8 __attribute__((ext_vector_type(8)));
typedef float f32x4 __attribute__((ext_vector_type(4)));
typedef unsigned short u16;
typedef unsigned int u32;

// Problem constants
static constexpr int Bn = 2, S = 2048, E = 1024, H = 16, D = 64;
static constexpr int Mrows = Bn * S;          // 4096
static constexpr int N_QKV = 3 * E;           // 3072

DEVI u16 f2b(float f) {
  union { float f; u32 u; } c; c.f = f;
  return (u16)((c.u + 0x7FFFu + ((c.u >> 16) & 1u)) >> 16);
}

DEVI bf16x8 ld8(const u16* p) {
  union { uint4 u; bf16x8 v; } c;
  c.u = *reinterpret_cast<const uint4*>(p);
  return c.v;
}

#define MFMA(a, b, c) __builtin_amdgcn_mfma_f32_16x16x32_bf16(a, b, c, 0, 0, 0)

// global -> LDS async copy, 16B per lane. LDS dest must be wave-uniform-base + lane*16.
#define G2L16(gptr, lptr) \
  __builtin_amdgcn_global_load_lds((const __attribute__((address_space(1))) void*)(gptr), \
                                   (__attribute__((address_space(3))) void*)(lptr), 16, 0, 0)

// ---------------- Fused prep: transposes FIRST, conv LAST (r14 order) ----------------
__global__ __launch_bounds__(256) void prep(const float* __restrict__ x,
                                            const float* __restrict__ w_attn,
                                            const float* __restrict__ w_proj,
                                            u16* __restrict__ xb, u16* __restrict__ wabT,
                                            u16* __restrict__ wpbT) {
  __shared__ float t[32][33];
  int blk = blockIdx.x, tid = threadIdx.x;
  if (blk >= 4096) {
    int i = (blk - 4096) * 256 + tid;          // n4 = 4096*1024/4 = 1048576
    float4 f = reinterpret_cast<const float4*>(x)[i];
    ushort4 u;
    u.x = f2b(f.x); u.y = f2b(f.y); u.z = f2b(f.z); u.w = f2b(f.w);
    reinterpret_cast<ushort4*>(xb)[i] = u;
    return;
  }
  const float* in; u16* out; int R, C, bx, by;
  if (blk < 3072) {
    in = w_attn; out = wabT; R = E; C = N_QKV;  // 96 x 32 tiles
    bx = (blk % 96) * 32; by = (blk / 96) * 32;
  } else {
    int q = blk - 3072;                         // 32 x 32 tiles
    in = w_proj; out = wpbT; R = E; C = E;
    bx = (q % 32) * 32; by = (q / 32) * 32;
  }
  int tx = tid & 31, ty = tid >> 5;             // 32 x 8
#pragma unroll
  for (int k = 0; k < 32; k += 8)
    t[ty + k][tx] = in[(size_t)(by + ty + k) * C + bx + tx];
  __syncthreads();
#pragma unroll
  for (int k = 0; k < 32; k += 8)
    out[(size_t)(bx + ty + k) * R + by + tx] = f2b(t[tx][ty + k]);
}

// ---------------- GEMM1: qkv = xb @ wabT^T, 128x64 tile, BK=64, XOR swizzle (r14) ---------
// r19: 128x128 tile REVERTED (r18: 510 TF, 50.6us, Occ 14%). Short K (16 steps) +
// scatter epilogue + halved grid (768 blocks = 3/CU) lose more to occupancy/tails than
// the doubled B-reuse gains. 128x64 = 1536 blocks = 6/CU, known <=43us.
// Q pre-scaled by log2e/8 so attn scores arrive in log2 domain (exp2 = bare v_exp_f32).
__global__ __launch_bounds__(256) void gemm_qkv(const u16* __restrict__ A, const u16* __restrict__ BT,
                                                u16* __restrict__ Qb, u16* __restrict__ Kb,
                                                u16* __restrict__ VbT) {
  constexpr int K = 1024, BK = 64;
  __shared__ __align__(16) u16 As[128 * BK];   // 16 KB, swizzled rows of 8 16B-groups
  __shared__ __align__(16) u16 Bs[64 * BK];    // 8 KB
  int tid = threadIdx.x;
  int w = tid >> 6, lane = tid & 63, quad = lane >> 4, l15 = lane & 15;
  int m0 = blockIdx.x * 128, n0 = blockIdx.y * 64;
  int mw = (w >> 1) * 64, nw = (w & 1) * 32;   // wave-tile 64x32
  const u16* Ab = A + (size_t)m0 * K;
  const u16* Bb = BT + (size_t)n0 * K;
  f32x4 acc[4][2] = {};
  for (int k0 = 0; k0 < K; k0 += BK) {
#pragma unroll
    for (int j = 0; j < 4; j++) {
      int L = j * 256 + tid;
      int row = L >> 3, cg = (L & 7) ^ (row & 7);
      G2L16(Ab + (size_t)row * K + k0 + cg * 8, (char*)As + L * 16);
    }
#pragma unroll
    for (int j = 0; j < 2; j++) {
      int L = j * 256 + tid;
      int row = L >> 3, cg = (L & 7) ^ (row & 7);
      G2L16(Bb + (size_t)row * K + k0 + cg * 8, (char*)Bs + L * 16);
    }
    __syncthreads();
#pragma unroll
    for (int kk = 0; kk < 2; kk++) {
      int sg = ((kk << 2) | quad) ^ (l15 & 7);   // swizzled 16B-group for this lane
      bf16x8 a[4], b[2];
#pragma unroll
      for (int i = 0; i < 4; i++) a[i] = ld8(&As[(mw + i * 16 + l15) * BK + sg * 8]);
#pragma unroll
      for (int i = 0; i < 2; i++) b[i] = ld8(&Bs[(nw + i * 16 + l15) * BK + sg * 8]);
#pragma unroll
      for (int mb = 0; mb < 4; mb++)
#pragma unroll
        for (int nb = 0; nb < 2; nb++)
          acc[mb][nb] = MFMA(a[mb], b[nb], acc[mb][nb]);
    }
    __syncthreads();
  }
#pragma unroll
  for (int mb = 0; mb < 4; mb++) {
    int m = m0 + mw + mb * 16 + quad * 4;      // rows m..m+3 (tiles never straddle batch)
    int b = m >> 11, s = m & 2047;
#pragma unroll
    for (int nb = 0; nb < 2; nb++) {
      int n = n0 + nw + nb * 16 + l15;
      int sec = n >> 10, e = n & 1023, h = e >> 6, d = e & 63;
      int bh = b * H + h;
      if (sec == 0) {
#pragma unroll
        for (int r = 0; r < 4; r++)
          Qb[((size_t)bh * S + s + r) * D + d] = f2b(acc[mb][nb][r] * 0.1803368801111244f);
      } else if (sec == 1) {
#pragma unroll
        for (int r = 0; r < 4; r++)
          Kb[((size_t)bh * S + s + r) * D + d] = f2b(acc[mb][nb][r]);
      } else {
        ushort4 v;
        v.x = f2b(acc[mb][nb][0]); v.y = f2b(acc[mb][nb][1]);
        v.z = f2b(acc[mb][nb][2]); v.w = f2b(acc[mb][nb][3]);
        *reinterpret_cast<ushort4*>(VbT + ((size_t)bh * D + d) * S + s) = v;
      }
    }
  }
}

// ---------------- Flash attention: P-slice interleave, 4 blocks/CU (r19) ----------------
// Staged K/V via global_load_lds kept (r17 showed de-staging is a 5x loss: direct global
// K/V loads put ~200cy L2 latency on the MFMA critical path). r19 change: the P buffer is
// WAVE-PRIVATE (pure lane-redistribution between QK^T output and PV input layouts), and PV
// consumes P in 32-key slices -- so interleave per 32-key chunk: 2 QK^T subtiles -> 16x32
// P slice -> PV. P shrinks 17.4KB -> 5KB; LDS 49.8 -> 37.9KB -> 4 blocks/CU = 16 waves/CU
// (was 3/12). P row stride 40 u16 (16B-aligned rows, 2-way-max banks; old stride-136
// pattern produced 1.65M bank conflicts). All 1024 blocks now co-resident: heavy-first
// replaced by balanced qt permutation -- co-resident quadruples (stride-256) get qts
// {a, 15-a, 16+a, 31-a}, constant work-sum 62 (was 48..76 spread). T5 setprio on MFMA
// clusters (m191: attn +4-7%). Fixed-max softmax (m==0, log2-domain); exp2+perm pack.
__global__ __launch_bounds__(256, 4) void attn(const u16* __restrict__ Qb, const u16* __restrict__ Kb,
                                               const u16* __restrict__ VbT, u16* __restrict__ Yb) {
  __shared__ __align__(16) u16 Ks[128 * 64];    // swizzled: (row, cg) at row*64 + (cg^(row&7))*8
  __shared__ __align__(16) u16 Vs[64 * 128];    // swizzled: (d, cg) at d*128 + (cg^(d&15))*8
  __shared__ __align__(16) u32 Ps[4][16 * 20];  // per-wave P slice [q=16][k=32] bf16, stride 20 u32
  int w = threadIdx.x >> 6, lane = threadIdx.x & 63, quad = lane >> 4, l15 = lane & 15;
  int blk = blockIdx.x;
  int bh = blk & 31;                 // same-bh -> same-XCD (blk%8 == bh%8)
  int g = blk >> 5;                  // 0..31
  int ga = g & 7, gb = g >> 3;       // co-resident quadruple shares ga (stride-256 blocks)
  int qt = ((gb & 2) << 3) + ((gb & 1) ? (15 - ga) : ga);   // balanced: quadruple sums 62
  int b = bh >> 4, h = bh & 15;
  int nc = (qt + 2) >> 1;            // staged 128-key chunks

  const u16* Kbh = Kb + (size_t)bh * S * D;
  const u16* Vbh = VbT + (size_t)bh * D * S;
  u32* myP = &Ps[w][0];
  const u16* myP16 = (const u16*)myP;

  int q_base = qt * 64 + w * 16;
  int qrow = q_base + l15;
  int kmax = q_base + 16;            // causal: this wave needs keys [0, kmax)

  const u16* Qp = Qb + ((size_t)bh * S + qrow) * D + quad * 8;
  bf16x8 bq0 = ld8(Qp), bq1 = ld8(Qp + 32);

  float lpart = 0.f;
  f32x4 o[4] = {};

  for (int c = 0; c < nc; c++) {
    int kbase = c * 128;
    __syncthreads();                 // previous chunk's readers done
    // ---- cooperative staging: K tile (16KB) ----
    const u16* Kg = Kbh + (size_t)kbase * D;
#pragma unroll
    for (int j = 0; j < 4; j++) {
      int L = (w * 4 + j) * 64 + lane;
      int row = L >> 3, cg = (L & 7) ^ (row & 7);
      G2L16(Kg + (size_t)row * 64 + cg * 8, (char*)Ks + L * 16);
    }
    // ---- cooperative staging: V^T tile (16KB) ----
    const u16* Vg = Vbh + kbase;
#pragma unroll
    for (int j = 0; j < 4; j++) {
      int L = (w * 4 + j) * 64 + lane;
      int row = L >> 4, cg = (L & 15) ^ (row & 15);
      G2L16(Vg + (size_t)row * S + cg * 8, (char*)Vs + L * 16);
    }
    __syncthreads();                 // staging visible (barrier drains vmcnt)

    // ---- per 32-key chunk: QK^T pair -> P slice -> PV (P is wave-private) ----
#pragma unroll
    for (int ch = 0; ch < 4; ch++) {
      int kc = kbase + ch * 32;
      if (kc < kmax) {               // wave-uniform
#pragma unroll
        for (int half = 0; half < 2; half++) {
          int kb = kc + half * 16;
          u32 pa = 0, pb = 0;
          if (kb < kmax) {           // wave-uniform
            int row = (ch * 2 + half) * 16 + l15;
            bf16x8 ak0 = ld8(&Ks[row * 64 + ((quad ^ (row & 7)) * 8)]);
            bf16x8 ak1 = ld8(&Ks[row * 64 + (((quad + 4) ^ (row & 7)) * 8)]);
            f32x4 z = {};
            __builtin_amdgcn_s_setprio(1);
            z = MFMA(ak0, bq0, z);
            z = MFMA(ak1, bq1, z);
            __builtin_amdgcn_s_setprio(0);
            if (kb == q_base) {      // diagonal subtile: mask k > q
#pragma unroll
              for (int r = 0; r < 4; r++)
                if (quad * 4 + r > l15) z[r] = -1e30f;
            }
            float p0 = __builtin_amdgcn_exp2f(z[0]);
            float p1 = __builtin_amdgcn_exp2f(z[1]);
            float p2 = __builtin_amdgcn_exp2f(z[2]);
            float p3 = __builtin_amdgcn_exp2f(z[3]);
            lpart += (p0 + p1) + (p2 + p3);
            union { float f; u32 u; } c0, c1, c2, c3;
            c0.f = p0; c1.f = p1; c2.f = p2; c3.f = p3;
            pa = __builtin_amdgcn_perm(c1.u + 0x8000u, c0.u + 0x8000u, 0x07060302u);
            pb = __builtin_amdgcn_perm(c3.u + 0x8000u, c2.u + 0x8000u, 0x07060302u);
          }
          uint2 pw; pw.x = pa; pw.y = pb;
          *reinterpret_cast<uint2*>(&myP[l15 * 20 + quad * 2 + half * 8]) = pw;  // ds_write_b64
        }
        // PV on this 32-key slice (compiler inserts lgkmcnt for the LDS RAW)
        bf16x8 bp = ld8(myP16 + l15 * 40 + quad * 8);
        __builtin_amdgcn_s_setprio(1);
#pragma unroll
        for (int dd = 0; dd < 4; dd++) {
          int rv = dd * 16 + l15;
          bf16x8 av = ld8(&Vs[rv * 128 + (((ch * 4 + quad) ^ (rv & 15)) * 8)]);
          o[dd] = MFMA(av, bp, o[dd]);
        }
        __builtin_amdgcn_s_setprio(0);
      }
    }
  }

  // ---- epilogue: each wave owns the full k-range of its 16 q-rows ----
  float l = lpart;
  l += __shfl_xor(l, 16);
  l += __shfl_xor(l, 32);
  float rinv = 1.0f / l;
  u16* Yp = Yb + ((size_t)b * S + qrow) * E + h * 64 + quad * 4;
#pragma unroll
  for (int dd = 0; dd < 4; dd++) {
    ushort4 y;
    y.x = f2b(o[dd][0] * rinv); y.y = f2b(o[dd][1] * rinv);
    y.z = f2b(o[dd][2] * rinv); y.w = f2b(o[dd][3] * rinv);
    *reinterpret_cast<ushort4*>(Yp + dd * 16) = y;
  }
}

// ---------------- GEMM2: out = Yb @ wpbT^T, 128x64 tile (512 blocks = 2/CU), fp32 out ----
__global__ __launch_bounds__(256) void gemm_proj(const u16* __restrict__ A, const u16* __restrict__ BT,
                                                 float* __restrict__ out) {
  constexpr int K = 1024, BK = 64;
  __shared__ __align__(16) u16 As[128 * BK];   // 16 KB
  __shared__ __align__(16) u16 Bs[64 * BK];    // 8 KB
  int tid = threadIdx.x;
  int w = tid >> 6, lane = tid & 63, quad = lane >> 4, l15 = lane & 15;
  int m0 = blockIdx.x * 128, n0 = blockIdx.y * 64;
  int mw = (w >> 1) * 64, nw = (w & 1) * 32;
  const u16* Ab = A + (size_t)m0 * K;
  const u16* Bb = BT + (size_t)n0 * K;
  f32x4 acc[4][2] = {};
  for (int k0 = 0; k0 < K; k0 += BK) {
#pragma unroll
    for (int j = 0; j < 4; j++) {
      int L = j * 256 + tid;
      int row = L >> 3, cg = (L & 7) ^ (row & 7);
      G2L16(Ab + (size_t)row * K + k0 + cg * 8, (char*)As + L * 16);
    }
#pragma unroll
    for (int j = 0; j < 2; j++) {
      int L = j * 256 + tid;
      int row = L >> 3, cg = (L & 7) ^ (row & 7);
      G2L16(Bb + (size_t)row * K + k0 + cg * 8, (char*)Bs + L * 16);
    }
    __syncthreads();
#pragma unroll
    for (int kk = 0; kk < 2; kk++) {
      int sg = ((kk << 2) | quad) ^ (l15 & 7);
      bf16x8 a[4], b[2];
#pragma unroll
      for (int i = 0; i < 4; i++) a[i] = ld8(&As[(mw + i * 16 + l15) * BK + sg * 8]);
#pragma unroll
      for (int i = 0; i < 2; i++) b[i] = ld8(&Bs[(nw + i * 16 + l15) * BK + sg * 8]);
#pragma unroll
      for (int mb = 0; mb < 4; mb++)
#pragma unroll
        for (int nb = 0; nb < 2; nb++)
          acc[mb][nb] = MFMA(a[mb], b[nb], acc[mb][nb]);
    }
    __syncthreads();
  }
#pragma unroll
  for (int mb = 0; mb < 4; mb++) {
    int m = m0 + mw + mb * 16 + quad * 4;
#pragma unroll
    for (int nb = 0; nb < 2; nb++) {
      int n = n0 + nw + nb * 16 + l15;
#pragma unroll
      for (int r = 0; r < 4; r++)
        out[(size_t)(m + r) * E + n] = acc[mb][nb][r];
    }
  }
}

extern "C" void kernel_launch(void* const* d_in, const int* in_sizes, int n_in,
                              void* d_out, int out_size, void* d_ws, size_t ws_size,
                              hipStream_t stream) {
  const float* x = (const float*)d_in[0];
  const float* w_attn = (const float*)d_in[1];
  const float* w_proj = (const float*)d_in[2];
  float* out = (float*)d_out;
  char* ws = (char*)d_ws;

  // workspace layout (bytes)
  u16* xb   = (u16*)(ws);                      // 4096*1024*2 = 8 MB
  u16* wabT = (u16*)(ws + 8388608);            // 3072*1024*2 = 6 MB
  u16* wpbT = (u16*)(ws + 14680064);           // 1024*1024*2 = 2 MB
  u16* Qb   = (u16*)(ws + 16777216);           // 8 MB
  u16* Kb   = (u16*)(ws + 25165824);           // 8 MB
  u16* VbT  = (u16*)(ws + 33554432);           // 8 MB
  u16* Yb   = (u16*)(ws + 41943040);           // 8 MB   (total 48 MB)

  prep<<<8192, 256, 0, stream>>>(x, w_attn, w_proj, xb, wabT, wpbT);
  gemm_qkv<<<dim3(Mrows / 128, N_QKV / 64), 256, 0, stream>>>(xb, wabT, Qb, Kb, VbT);
  attn<<<Bn * H * (S / 64), 256, 0, stream>>>(Qb, Kb, VbT, Yb);
  gemm_proj<<<dim3(Mrows / 128, E / 64), 256, 0, stream>>>(Yb, wpbT, out);
}

// Round 4
// 171.892 us; speedup vs baseline: 1.0171x; 1.0171x over previous
//
#include <hip/hip_runtime.h>

#define DEVI __device__ __forceinline__

typedef short bf16x8 __attribute__((ext_vector_type(8)));
typedef float f32x4 __attribute__((ext_vector_type(4)));
typedef unsigned short u16;
typedef unsigned int u32;

// Problem constants
static constexpr int Bn = 2, S = 2048, E = 1024, H = 16, D = 64;
static constexpr int Mrows = Bn * S;          // 4096
static constexpr int N_QKV = 3 * E;           // 3072

DEVI u16 f2b(float f) {
  union { float f; u32 u; } c; c.f = f;
  return (u16)((c.u + 0x7FFFu + ((c.u >> 16) & 1u)) >> 16);
}

DEVI bf16x8 ld8(const u16* p) {
  union { uint4 u; bf16x8 v; } c;
  c.u = *reinterpret_cast<const uint4*>(p);
  return c.v;
}

#define MFMA(a, b, c) __builtin_amdgcn_mfma_f32_16x16x32_bf16(a, b, c, 0, 0, 0)

// global -> LDS async copy, 16B per lane. LDS dest must be wave-uniform-base + lane*16.
#define G2L16(gptr, lptr) \
  __builtin_amdgcn_global_load_lds((const __attribute__((address_space(1))) void*)(gptr), \
                                   (__attribute__((address_space(3))) void*)(lptr), 16, 0, 0)

// ---------------- Fused prep: transposes FIRST, conv LAST (r14 order) ----------------
__global__ __launch_bounds__(256) void prep(const float* __restrict__ x,
                                            const float* __restrict__ w_attn,
                                            const float* __restrict__ w_proj,
                                            u16* __restrict__ xb, u16* __restrict__ wabT,
                                            u16* __restrict__ wpbT) {
  __shared__ float t[32][33];
  int blk = blockIdx.x, tid = threadIdx.x;
  if (blk >= 4096) {
    int i = (blk - 4096) * 256 + tid;          // n4 = 4096*1024/4 = 1048576
    float4 f = reinterpret_cast<const float4*>(x)[i];
    ushort4 u;
    u.x = f2b(f.x); u.y = f2b(f.y); u.z = f2b(f.z); u.w = f2b(f.w);
    reinterpret_cast<ushort4*>(xb)[i] = u;
    return;
  }
  const float* in; u16* out; int R, C, bx, by;
  if (blk < 3072) {
    in = w_attn; out = wabT; R = E; C = N_QKV;  // 96 x 32 tiles
    bx = (blk % 96) * 32; by = (blk / 96) * 32;
  } else {
    int q = blk - 3072;                         // 32 x 32 tiles
    in = w_proj; out = wpbT; R = E; C = E;
    bx = (q % 32) * 32; by = (q / 32) * 32;
  }
  int tx = tid & 31, ty = tid >> 5;             // 32 x 8
#pragma unroll
  for (int k = 0; k < 32; k += 8)
    t[ty + k][tx] = in[(size_t)(by + ty + k) * C + bx + tx];
  __syncthreads();
#pragma unroll
  for (int k = 0; k < 32; k += 8)
    out[(size_t)(bx + ty + k) * R + by + tx] = f2b(t[tx][ty + k]);
}

// ---------------- GEMM1: qkv = xb @ wabT^T, 128x64 tile, BK=64, XOR swizzle (r14) ---------
// r19: 128x128 tile REVERTED (r18: 510 TF, 50.6us, Occ 14%). Short K (16 steps) +
// scatter epilogue + halved grid (768 blocks = 3/CU) lose more to occupancy/tails than
// the doubled B-reuse gains. 128x64 = 1536 blocks = 6/CU, known <=43us.
// Q pre-scaled by log2e/8 so attn scores arrive in log2 domain (exp2 = bare v_exp_f32).
__global__ __launch_bounds__(256) void gemm_qkv(const u16* __restrict__ A, const u16* __restrict__ BT,
                                                u16* __restrict__ Qb, u16* __restrict__ Kb,
                                                u16* __restrict__ VbT) {
  constexpr int K = 1024, BK = 64;
  __shared__ __align__(16) u16 As[128 * BK];   // 16 KB, swizzled rows of 8 16B-groups
  __shared__ __align__(16) u16 Bs[64 * BK];    // 8 KB
  int tid = threadIdx.x;
  int w = tid >> 6, lane = tid & 63, quad = lane >> 4, l15 = lane & 15;
  int m0 = blockIdx.x * 128, n0 = blockIdx.y * 64;
  int mw = (w >> 1) * 64, nw = (w & 1) * 32;   // wave-tile 64x32
  const u16* Ab = A + (size_t)m0 * K;
  const u16* Bb = BT + (size_t)n0 * K;
  f32x4 acc[4][2] = {};
  for (int k0 = 0; k0 < K; k0 += BK) {
#pragma unroll
    for (int j = 0; j < 4; j++) {
      int L = j * 256 + tid;
      int row = L >> 3, cg = (L & 7) ^ (row & 7);
      G2L16(Ab + (size_t)row * K + k0 + cg * 8, (char*)As + L * 16);
    }
#pragma unroll
    for (int j = 0; j < 2; j++) {
      int L = j * 256 + tid;
      int row = L >> 3, cg = (L & 7) ^ (row & 7);
      G2L16(Bb + (size_t)row * K + k0 + cg * 8, (char*)Bs + L * 16);
    }
    __syncthreads();
#pragma unroll
    for (int kk = 0; kk < 2; kk++) {
      int sg = ((kk << 2) | quad) ^ (l15 & 7);   // swizzled 16B-group for this lane
      bf16x8 a[4], b[2];
#pragma unroll
      for (int i = 0; i < 4; i++) a[i] = ld8(&As[(mw + i * 16 + l15) * BK + sg * 8]);
#pragma unroll
      for (int i = 0; i < 2; i++) b[i] = ld8(&Bs[(nw + i * 16 + l15) * BK + sg * 8]);
#pragma unroll
      for (int mb = 0; mb < 4; mb++)
#pragma unroll
        for (int nb = 0; nb < 2; nb++)
          acc[mb][nb] = MFMA(a[mb], b[nb], acc[mb][nb]);
    }
    __syncthreads();
  }
#pragma unroll
  for (int mb = 0; mb < 4; mb++) {
    int m = m0 + mw + mb * 16 + quad * 4;      // rows m..m+3 (tiles never straddle batch)
    int b = m >> 11, s = m & 2047;
#pragma unroll
    for (int nb = 0; nb < 2; nb++) {
      int n = n0 + nw + nb * 16 + l15;
      int sec = n >> 10, e = n & 1023, h = e >> 6, d = e & 63;
      int bh = b * H + h;
      if (sec == 0) {
#pragma unroll
        for (int r = 0; r < 4; r++)
          Qb[((size_t)bh * S + s + r) * D + d] = f2b(acc[mb][nb][r] * 0.1803368801111244f);
      } else if (sec == 1) {
#pragma unroll
        for (int r = 0; r < 4; r++)
          Kb[((size_t)bh * S + s + r) * D + d] = f2b(acc[mb][nb][r]);
      } else {
        ushort4 v;
        v.x = f2b(acc[mb][nb][0]); v.y = f2b(acc[mb][nb][1]);
        v.z = f2b(acc[mb][nb][2]); v.w = f2b(acc[mb][nb][3]);
        *reinterpret_cast<ushort4*>(VbT + ((size_t)bh * D + d) * S + s) = v;
      }
    }
  }
}

// ---------------- Flash attention: DOUBLE-BUFFERED staging, counted vmcnt (r20) ----------
// r19 P-slice interleave REVERTED (50.4us vs ~42: per-slice ds_write->ds_read RAW
// serialization cost > occupancy gain). r20 attacks the REAL stall: per chunk-gen per CU,
// staging (~710cy L2) and compute (~660cy) are balanced but strictly SERIALIZED by the
// stage -> vmcnt(0)-drain barrier -> compute structure. Fix = T3/T4 minimal recipe:
// chunk 64 keys, double-buffered K/V (2x8KB each); issue next chunk's 4 global_load_lds
// BEFORE computing current, then counted `s_waitcnt vmcnt(4)` (never 0 mid-loop) + raw
// s_barrier -> next chunk's loads stay in flight across the barrier. sched_barrier(0)
// after the wait (rule #18); explicit lgkmcnt(0) before trailing barrier; vmcnt(0) only
// on the last iteration. LDS 41KB -> 3 blocks/CU (as round-0) but staging now overlaps.
// Compute body = round-0 (full-subtile QK^T -> wave-private P -> PV), heavy-first qt,
// fixed-max log2-domain softmax, exp2+perm pack, T5 setprio on MFMA clusters.
__global__ __launch_bounds__(256, 3) void attn(const u16* __restrict__ Qb, const u16* __restrict__ Kb,
                                               const u16* __restrict__ VbT, u16* __restrict__ Yb) {
  __shared__ __align__(16) u16 Ks[2][64 * 64];  // swizzled: (row, cg) at row*64 + (cg^(row&7))*8
  __shared__ __align__(16) u16 Vs[2][64 * 64];  // swizzled: (d, cg) at d*64 + (cg^(d&7))*8
  __shared__ __align__(16) u32 Ps[4][16 * 36];  // per-wave P[q=16][k=64] bf16, stride 36 u32
  int w = threadIdx.x >> 6, lane = threadIdx.x & 63, quad = lane >> 4, l15 = lane & 15;
  int bh = blockIdx.x & 31, qt = 31 - (blockIdx.x >> 5);   // heavy q-tiles first
  int b = bh >> 4, h = bh & 15;
  int nc = qt + 1;                   // 64-key chunks this block needs

  const u16* Kbh = Kb + (size_t)bh * S * D;
  const u16* Vbh = VbT + (size_t)bh * D * S;
  u32* myP = &Ps[w][0];
  const u16* myP16 = (const u16*)myP;

  int q_base = qt * 64 + w * 16;
  int qrow = q_base + l15;
  int kmax = q_base + 16;            // causal: this wave needs keys [0, kmax)

  const u16* Qp = Qb + ((size_t)bh * S + qrow) * D + quad * 8;
  bf16x8 bq0 = ld8(Qp), bq1 = ld8(Qp + 32);

  float lpart = 0.f;
  f32x4 o[4] = {};

  // ---- prologue: stage chunk 0 into buffer 0 (4 G2L16 per wave) ----
#pragma unroll
  for (int j = 0; j < 2; j++) {
    int L = (w * 2 + j) * 64 + lane;           // 0..511
    int row = L >> 3, cg = (L & 7) ^ (row & 7);
    G2L16(Kbh + (size_t)row * D + cg * 8, (char*)Ks[0] + L * 16);
  }
#pragma unroll
  for (int j = 0; j < 2; j++) {
    int L = (w * 2 + j) * 64 + lane;
    int row = L >> 3, cg = (L & 7) ^ (row & 7);
    G2L16(Vbh + (size_t)row * S + cg * 8, (char*)Vs[0] + L * 16);
  }

  for (int c = 0; c < nc; c++) {
    int kbase = c * 64;
    int cur = c & 1;
    if (c + 1 < nc) {
      // ---- issue next chunk's staging into the other buffer, then counted wait ----
      const u16* Kg = Kbh + (size_t)(kbase + 64) * D;
      const u16* Vg = Vbh + (kbase + 64);
#pragma unroll
      for (int j = 0; j < 2; j++) {
        int L = (w * 2 + j) * 64 + lane;
        int row = L >> 3, cg = (L & 7) ^ (row & 7);
        G2L16(Kg + (size_t)row * D + cg * 8, (char*)Ks[cur ^ 1] + L * 16);
      }
#pragma unroll
      for (int j = 0; j < 2; j++) {
        int L = (w * 2 + j) * 64 + lane;
        int row = L >> 3, cg = (L & 7) ^ (row & 7);
        G2L16(Vg + (size_t)row * S + cg * 8, (char*)Vs[cur ^ 1] + L * 16);
      }
      asm volatile("s_waitcnt vmcnt(4)" ::: "memory");   // chunk c landed; c+1 in flight
    } else {
      asm volatile("s_waitcnt vmcnt(0)" ::: "memory");   // final chunk: drain
    }
    __builtin_amdgcn_s_barrier();
    __builtin_amdgcn_sched_barrier(0);

    const u16* Kc = Ks[cur];
    const u16* Vc = Vs[cur];

    // ---- QK^T + exp2 + perm-pack into wave-private P (4 subtiles of 16 keys) ----
#pragma unroll
    for (int mb = 0; mb < 4; mb++) {
      int kb = kbase + mb * 16;
      u32 pa = 0, pb = 0;
      if (kb < kmax) {               // wave-uniform
        int row = mb * 16 + l15;
        bf16x8 ak0 = ld8(&Kc[row * 64 + ((quad ^ (row & 7)) * 8)]);
        bf16x8 ak1 = ld8(&Kc[row * 64 + (((quad + 4) ^ (row & 7)) * 8)]);
        f32x4 z = {};
        __builtin_amdgcn_s_setprio(1);
        z = MFMA(ak0, bq0, z);
        z = MFMA(ak1, bq1, z);
        __builtin_amdgcn_s_setprio(0);
        if (kb == q_base) {          // diagonal subtile: mask k > q
#pragma unroll
          for (int r = 0; r < 4; r++)
            if (quad * 4 + r > l15) z[r] = -1e30f;
        }
        float p0 = __builtin_amdgcn_exp2f(z[0]);
        float p1 = __builtin_amdgcn_exp2f(z[1]);
        float p2 = __builtin_amdgcn_exp2f(z[2]);
        float p3 = __builtin_amdgcn_exp2f(z[3]);
        lpart += (p0 + p1) + (p2 + p3);
        union { float f; u32 u; } c0, c1, c2, c3;
        c0.f = p0; c1.f = p1; c2.f = p2; c3.f = p3;
        pa = __builtin_amdgcn_perm(c1.u + 0x8000u, c0.u + 0x8000u, 0x07060302u);
        pb = __builtin_amdgcn_perm(c3.u + 0x8000u, c2.u + 0x8000u, 0x07060302u);
      }
      uint2 pw; pw.x = pa; pw.y = pb;
      *reinterpret_cast<uint2*>(&myP[l15 * 36 + quad * 2 + mb * 8]) = pw;   // ds_write_b64
    }
    // ---- O^T += V^T · P^T per 32-key chunk ----
#pragma unroll
    for (int ch = 0; ch < 2; ch++) {
      int kc = kbase + ch * 32;
      if (kc < kmax) {               // wave-uniform
        bf16x8 bp = ld8(myP16 + l15 * 72 + ch * 32 + quad * 8);
        __builtin_amdgcn_s_setprio(1);
#pragma unroll
        for (int dd = 0; dd < 4; dd++) {
          int rv = dd * 16 + l15;
          bf16x8 av = ld8(&Vc[rv * 64 + (((ch * 4 + quad) ^ (rv & 7)) * 8)]);
          o[dd] = MFMA(av, bp, o[dd]);
        }
        __builtin_amdgcn_s_setprio(0);
      }
    }
    asm volatile("s_waitcnt lgkmcnt(0)" ::: "memory");   // LDS reads done before release
    __builtin_amdgcn_s_barrier();    // buf[cur] free for iter c+1's stage of chunk c+2
  }

  // ---- epilogue: each wave owns the full k-range of its 16 q-rows ----
  float l = lpart;
  l += __shfl_xor(l, 16);
  l += __shfl_xor(l, 32);
  float rinv = 1.0f / l;
  u16* Yp = Yb + ((size_t)b * S + qrow) * E + h * 64 + quad * 4;
#pragma unroll
  for (int dd = 0; dd < 4; dd++) {
    ushort4 y;
    y.x = f2b(o[dd][0] * rinv); y.y = f2b(o[dd][1] * rinv);
    y.z = f2b(o[dd][2] * rinv); y.w = f2b(o[dd][3] * rinv);
    *reinterpret_cast<ushort4*>(Yp + dd * 16) = y;
  }
}

// ---------------- GEMM2: out = Yb @ wpbT^T, 128x64 tile (512 blocks = 2/CU), fp32 out ----
__global__ __launch_bounds__(256) void gemm_proj(const u16* __restrict__ A, const u16* __restrict__ BT,
                                                 float* __restrict__ out) {
  constexpr int K = 1024, BK = 64;
  __shared__ __align__(16) u16 As[128 * BK];   // 16 KB
  __shared__ __align__(16) u16 Bs[64 * BK];    // 8 KB
  int tid = threadIdx.x;
  int w = tid >> 6, lane = tid & 63, quad = lane >> 4, l15 = lane & 15;
  int m0 = blockIdx.x * 128, n0 = blockIdx.y * 64;
  int mw = (w >> 1) * 64, nw = (w & 1) * 32;
  const u16* Ab = A + (size_t)m0 * K;
  const u16* Bb = BT + (size_t)n0 * K;
  f32x4 acc[4][2] = {};
  for (int k0 = 0; k0 < K; k0 += BK) {
#pragma unroll
    for (int j = 0; j < 4; j++) {
      int L = j * 256 + tid;
      int row = L >> 3, cg = (L & 7) ^ (row & 7);
      G2L16(Ab + (size_t)row * K + k0 + cg * 8, (char*)As + L * 16);
    }
#pragma unroll
    for (int j = 0; j < 2; j++) {
      int L = j * 256 + tid;
      int row = L >> 3, cg = (L & 7) ^ (row & 7);
      G2L16(Bb + (size_t)row * K + k0 + cg * 8, (char*)Bs + L * 16);
    }
    __syncthreads();
#pragma unroll
    for (int kk = 0; kk < 2; kk++) {
      int sg = ((kk << 2) | quad) ^ (l15 & 7);
      bf16x8 a[4], b[2];
#pragma unroll
      for (int i = 0; i < 4; i++) a[i] = ld8(&As[(mw + i * 16 + l15) * BK + sg * 8]);
#pragma unroll
      for (int i = 0; i < 2; i++) b[i] = ld8(&Bs[(nw + i * 16 + l15) * BK + sg * 8]);
#pragma unroll
      for (int mb = 0; mb < 4; mb++)
#pragma unroll
        for (int nb = 0; nb < 2; nb++)
          acc[mb][nb] = MFMA(a[mb], b[nb], acc[mb][nb]);
    }
    __syncthreads();
  }
#pragma unroll
  for (int mb = 0; mb < 4; mb++) {
    int m = m0 + mw + mb * 16 + quad * 4;
#pragma unroll
    for (int nb = 0; nb < 2; nb++) {
      int n = n0 + nw + nb * 16 + l15;
#pragma unroll
      for (int r = 0; r < 4; r++)
        out[(size_t)(m + r) * E + n] = acc[mb][nb][r];
    }
  }
}

extern "C" void kernel_launch(void* const* d_in, const int* in_sizes, int n_in,
                              void* d_out, int out_size, void* d_ws, size_t ws_size,
                              hipStream_t stream) {
  const float* x = (const float*)d_in[0];
  const float* w_attn = (const float*)d_in[1];
  const float* w_proj = (const float*)d_in[2];
  float* out = (float*)d_out;
  char* ws = (char*)d_ws;

  // workspace layout (bytes)
  u16* xb   = (u16*)(ws);                      // 4096*1024*2 = 8 MB
  u16* wabT = (u16*)(ws + 8388608);            // 3072*1024*2 = 6 MB
  u16* wpbT = (u16*)(ws + 14680064);           // 1024*1024*2 = 2 MB
  u16* Qb   = (u16*)(ws + 16777216);           // 8 MB
  u16* Kb   = (u16*)(ws + 25165824);           // 8 MB
  u16* VbT  = (u16*)(ws + 33554432);           // 8 MB
  u16* Yb   = (u16*)(ws + 41943040);           // 8 MB   (total 48 MB)

  prep<<<8192, 256, 0, stream>>>(x, w_attn, w_proj, xb, wabT, wpbT);
  gemm_qkv<<<dim3(Mrows / 128, N_QKV / 64), 256, 0, stream>>>(xb, wabT, Qb, Kb, VbT);
  attn<<<Bn * H * (S / 64), 256, 0, stream>>>(Qb, Kb, VbT, Yb);
  gemm_proj<<<dim3(Mrows / 128, E / 64), 256, 0, stream>>>(Yb, wpbT, out);
}